// Round 2
// baseline (276.929 us; speedup 1.0000x reference)
//
#include <hip/hip_runtime.h>

#define NT 256

// LDS layout: XOR swizzle, exact 32 KB (4096 float2) -> 5 blocks/CU (was 36.8 KB pad -> 4).
// phys(l) = l ^ (((l>>4)&7)<<1): XORs the Q-digit (bits 4..6) into M-digit bits 1..3.
// Bijective. Conflict-free for every exchange pattern (bank-pair = phys mod 16):
//   ex1 w/r  l=256a+t:        bank4 = (t&15)^(((t>>4)&7)<<1)  bijection per 16-lane group
//   ex1r/ex2 l=256ax+16q+m2:  bank4 = m2^((q&7)<<1)           bijection in m2
//   ex2 b128 l=256ax+16m2+m:  bank4 = m^((m2&7)<<1)           uniform over even slots
// XOR leaves bit0 alone -> (2k,2k+1) pairs stay adjacent+ordered+16B-aligned for b128.

// 16-point DFT in registers: v[k] = sum_j v[j] * w16^{jk}, w16 = e^{-2pi i/16}
// (INV=true: conjugated; unnormalized). Natural order in/out.
template<bool INV>
__device__ __forceinline__ void dft16(float* vr, float* vi) {
    constexpr float C1 = 0.9238795325112867f;   // cos(pi/8)
    constexpr float S1 = 0.3826834323650898f;   // sin(pi/8)
    constexpr float HF = 0.7071067811865476f;
    const float WR[10] = {1.f,  C1,  HF,  S1, 0.f, 0.f, -HF, 0.f, 0.f, -C1};
    const float WI[10] = {0.f, -S1, -HF, -C1, -1.f, 0.f, -HF, 0.f, 0.f,  S1};

    float ar[16], ai[16];
    #pragma unroll
    for (int jl = 0; jl < 4; ++jl) {
        float x0r = vr[jl],      x0i = vi[jl];
        float x1r = vr[jl + 4],  x1i = vi[jl + 4];
        float x2r = vr[jl + 8],  x2i = vi[jl + 8];
        float x3r = vr[jl + 12], x3i = vi[jl + 12];
        float t0r = x0r + x2r, t0i = x0i + x2i;
        float t1r = x0r - x2r, t1i = x0i - x2i;
        float t2r = x1r + x3r, t2i = x1i + x3i;
        float t3r = x1r - x3r, t3i = x1i - x3i;
        ar[jl]     = t0r + t2r;  ai[jl]     = t0i + t2i;
        ar[jl + 8] = t0r - t2r;  ai[jl + 8] = t0i - t2i;
        if (!INV) {
            ar[jl + 4]  = t1r + t3i;  ai[jl + 4]  = t1i - t3r;  // t1 - i*t3
            ar[jl + 12] = t1r - t3i;  ai[jl + 12] = t1i + t3r;  // t1 + i*t3
        } else {
            ar[jl + 4]  = t1r - t3i;  ai[jl + 4]  = t1i + t3r;
            ar[jl + 12] = t1r + t3i;  ai[jl + 12] = t1i - t3r;
        }
    }
    #pragma unroll
    for (int k4 = 1; k4 < 4; ++k4) {
        #pragma unroll
        for (int jl = 1; jl < 4; ++jl) {
            const int e = jl * k4;
            float wr = WR[e];
            float wi = INV ? -WI[e] : WI[e];
            const int id = jl + 4 * k4;
            float xr = ar[id], xi = ai[id];
            ar[id] = xr * wr - xi * wi;
            ai[id] = xr * wi + xi * wr;
        }
    }
    #pragma unroll
    for (int k4 = 0; k4 < 4; ++k4) {
        float x0r = ar[4*k4 + 0], x0i = ai[4*k4 + 0];
        float x1r = ar[4*k4 + 1], x1i = ai[4*k4 + 1];
        float x2r = ar[4*k4 + 2], x2i = ai[4*k4 + 2];
        float x3r = ar[4*k4 + 3], x3i = ai[4*k4 + 3];
        float t0r = x0r + x2r, t0i = x0i + x2i;
        float t1r = x0r - x2r, t1i = x0i - x2i;
        float t2r = x1r + x3r, t2i = x1i + x3i;
        float t3r = x1r - x3r, t3i = x1i - x3i;
        vr[k4]     = t0r + t2r;  vi[k4]     = t0i + t2i;
        vr[k4 + 8] = t0r - t2r;  vi[k4 + 8] = t0i - t2i;
        if (!INV) {
            vr[k4 + 4]  = t1r + t3i;  vi[k4 + 4]  = t1i - t3r;
            vr[k4 + 12] = t1r - t3i;  vi[k4 + 12] = t1i + t3r;
        } else {
            vr[k4 + 4]  = t1r - t3i;  vi[k4 + 4]  = t1i + t3r;
            vr[k4 + 12] = t1r + t3i;  vi[k4 + 12] = t1i - t3r;
        }
    }
}

// v[e] *= (wr,wi)^e for e=1..15; two independent chains stepping by w^2
// (halves the serial complex-mul chain latency vs a single chain).
__device__ __forceinline__ void apply_tw_powers(float* vr, float* vi, float wr, float wi) {
    const float w2r = wr * wr - wi * wi;
    const float w2i = 2.0f * wr * wi;
    float aor = wr,  aoi = wi;    // odd powers: w^1, w^3, ...
    float aer = w2r, aei = w2i;   // even powers: w^2, w^4, ...
    #pragma unroll
    for (int e = 1; e < 16; e += 2) {
        { float xr = vr[e], xi = vi[e];
          vr[e] = xr * aor - xi * aoi;
          vi[e] = xr * aoi + xi * aor; }
        if (e + 1 < 16) {
            float xr = vr[e + 1], xi = vi[e + 1];
            vr[e + 1] = xr * aer - xi * aei;
            vi[e + 1] = xr * aei + xi * aer;
        }
        if (e + 2 < 16) {
            float nr = aor * w2r - aoi * w2i, ni = aor * w2i + aoi * w2r;
            aor = nr; aoi = ni;
            nr = aer * w2r - aei * w2i; ni = aer * w2i + aei * w2r;
            aer = nr; aei = ni;
        }
    }
}

__global__ __launch_bounds__(NT, 5) void spectral_circulant_r16v4(
    const float* __restrict__ x,
    const float* __restrict__ w_real,
    const float* __restrict__ w_imag,
    const float* __restrict__ bias_p,
    float* __restrict__ out)
{
    __shared__ __align__(16) float2 lds[4096];   // exactly 32 KB -> 5 blocks/CU

    const int t   = threadIdx.x;
    const int blk = blockIdx.x;

    float vr[16], vi[16];

    // ---- load two rows: z = rowA + i*rowB; reg j holds x[256j + t] ----
    const float* __restrict__ xa = x + (size_t)(2 * blk) * 4096;
    const float* __restrict__ xb = xa + 4096;
    #pragma unroll
    for (int j = 0; j < 16; ++j) {
        vr[j] = xa[(j << 8) + t];
        vi[j] = xb[(j << 8) + t];
    }

    // ---- stage A: DFT16 over j -> digit a; twiddle W4096^{t*a} ----
    dft16<false>(vr, vi);
    float sA, cA;
    __sincosf((float)t * -1.5339807878856412e-3f, &sA, &cA);  // -2pi/4096
    apply_tw_powers(vr, vi, cA, sA);

    // ---- exchange 1 write: l = 256a + t (b64); phys = 256a + tswz ----
    {
        const int tswz = t ^ ((t >> 3) & 0xE);   // t ^ (((t>>4)&7)<<1)
        #pragma unroll
        for (int a = 0; a < 16; ++a)
            lds[(a << 8) + tswz] = make_float2(vr[a], vi[a]);
    }
    __syncthreads();

    const int ax = t >> 4;               // upper digit this thread owns from here on
    const int m2 = t & 15;               // lower digit

    // 8 swizzled column bases: phys(256ax + 16q + m2) = swzbase[q&7] + 16q.
    // Shared by ex1-read, ex2-write, ex2-rev-read, ex1-rev-write (same l-set).
    int swzbase[8];
    #pragma unroll
    for (int c = 0; c < 8; ++c)
        swzbase[c] = (ax << 8) + (m2 ^ (c << 1));

    // ---- exchange 1 read: l = 256ax + 16q + m2 (b64) ----
    #pragma unroll
    for (int q = 0; q < 16; ++q) {
        float2 v = lds[swzbase[q & 7] + (q << 4)];
        vr[q] = v.x; vi[q] = v.y;
    }

    // ---- stage B: DFT16 over q -> digit b; twiddle W256^{m2*b} ----
    dft16<false>(vr, vi);
    float sB, cB;
    __sincosf((float)m2 * -2.454369260617026e-2f, &sB, &cB);  // -2pi/256
    apply_tw_powers(vr, vi, cB, sB);

    // ---- exchange 2 write: l = 256ax + 16b + m2 (b64) — same set this thread
    // read. Moves data only within 16 consecutive threads (same wave): per-wave
    // in-order DS pipe + compiler scheduling barrier suffice, no block barrier.
    #pragma unroll
    for (int b = 0; b < 16; ++b)
        lds[swzbase[b & 7] + (b << 4)] = make_float2(vr[b], vi[b]);
    __builtin_amdgcn_wave_barrier();

    // ---- exchange 2 read: 16 contiguous at l0 = 256ax + 16*m2;
    // phys = l0 + (m ^ c2), c2 even -> pairs stay aligned+ordered (b128) ----
    const int c2 = (m2 & 7) << 1;
    const float2* __restrict__ pbase = &lds[(ax << 8) + (m2 << 4)];
    #pragma unroll
    for (int m = 0; m < 16; m += 2) {
        float4 v = *(const float4*)&pbase[m ^ c2];
        vr[m] = v.x;     vi[m] = v.y;
        vr[m + 1] = v.z; vi[m + 1] = v.w;
    }

    // ---- stage C: DFT16 over m -> digit r3; freq k = 256*r3 + 16*m2 + ax ----
    dft16<false>(vr, vi);

    // ---- pointwise H[k]/N ----
    {
        const int c = (m2 << 4) | ax;            // 16*b + a  in [0,255]
        const float sc = 1.0f / 4096.0f;
        #pragma unroll
        for (int r3 = 0; r3 < 4; ++r3) {         // k < 1024: active
            const int k = (r3 << 8) + c;
            float hr = w_real[k] * sc;
            float hi = w_imag[k] * sc;
            float xr = vr[r3], xi = vi[r3];
            vr[r3] = xr * hr - xi * hi;
            vi[r3] = xr * hi + xi * hr;
        }
        #pragma unroll
        for (int r3 = 4; r3 < 12; ++r3) {        // k in [1024,3071]: truncated
            vr[r3] = 0.0f; vi[r3] = 0.0f;
        }
        {                                        // r3=12: k=3072+c, active iff c>0
            const int idx = 1024 - c;
            const float m = (c > 0) ? sc : 0.0f;
            float hr = w_real[idx] * m;
            float hi = -w_imag[idx] * m;
            float xr = vr[12], xi = vi[12];
            vr[12] = xr * hr - xi * hi;
            vi[12] = xr * hi + xi * hr;
        }
        #pragma unroll
        for (int r3 = 13; r3 < 16; ++r3) {       // k > 3072: conj mirror
            const int idx = ((16 - r3) << 8) - c;
            float hr = w_real[idx] * sc;
            float hi = -w_imag[idx] * sc;
            float xr = vr[r3], xi = vi[r3];
            vr[r3] = xr * hr - xi * hi;
            vi[r3] = xr * hi + xi * hr;
        }
    }

    // ================= inverse: exact adjoint, reverse order =================

    // ---- C^H: conj DFT16 over r3 -> m ----
    dft16<true>(vr, vi);

    // ---- exchange 2 reverse write: same contiguous-set addresses (b128) ----
    {
        float2* __restrict__ pw = &lds[(ax << 8) + (m2 << 4)];
        #pragma unroll
        for (int m = 0; m < 16; m += 2)
            *(float4*)&pw[m ^ c2] = make_float4(vr[m], vi[m], vr[m + 1], vi[m + 1]);
    }
    __builtin_amdgcn_wave_barrier();

    // ---- exchange 2 reverse read: l = 256ax + 16b + m2 over b (b64) ----
    #pragma unroll
    for (int b = 0; b < 16; ++b) {
        float2 v = lds[swzbase[b & 7] + (b << 4)];
        vr[b] = v.x; vi[b] = v.y;
    }

    // ---- B^H: conj twiddle, conj DFT16 over b -> q ----
    apply_tw_powers(vr, vi, cB, -sB);
    dft16<true>(vr, vi);

    // ---- exchange 1 reverse write: l = 256ax + 16q + m2 (same set, b64) ----
    #pragma unroll
    for (int q = 0; q < 16; ++q)
        lds[swzbase[q & 7] + (q << 4)] = make_float2(vr[q], vi[q]);
    __syncthreads();

    // ---- exchange 1 reverse read: l = 256a + t (b64) ----
    {
        const int tswz = t ^ ((t >> 3) & 0xE);
        #pragma unroll
        for (int a = 0; a < 16; ++a) {
            float2 v = lds[(a << 8) + tswz];
            vr[a] = v.x; vi[a] = v.y;
        }
    }

    // ---- A^H: conj twiddle, conj DFT16 over a -> j ----
    apply_tw_powers(vr, vi, cA, -sA);
    dft16<true>(vr, vi);

    // ---- store (nontemporal: streamed output) ----
    const float bv = bias_p[0];
    float* __restrict__ oa = out + (size_t)(2 * blk) * 4096;
    float* __restrict__ ob = oa + 4096;
    #pragma unroll
    for (int j = 0; j < 16; ++j) {
        __builtin_nontemporal_store(vr[j] + bv, &oa[(j << 8) + t]);
        __builtin_nontemporal_store(vi[j] + bv, &ob[(j << 8) + t]);
    }
}

extern "C" void kernel_launch(void* const* d_in, const int* in_sizes, int n_in,
                              void* d_out, int out_size, void* d_ws, size_t ws_size,
                              hipStream_t stream) {
    (void)in_sizes; (void)n_in; (void)d_ws; (void)ws_size; (void)out_size;
    const float* x      = (const float*)d_in[0];   // (8192, 4096) f32
    const float* w_real = (const float*)d_in[1];   // (2049,) f32
    const float* w_imag = (const float*)d_in[2];   // (2049,) f32
    const float* bias   = (const float*)d_in[3];   // scalar f32
    float* out = (float*)d_out;                    // (8192, 4096) f32

    spectral_circulant_r16v4<<<8192 / 2, NT, 0, stream>>>(x, w_real, w_imag, bias, out);
}

// Round 3
// 242.048 us; speedup vs baseline: 1.1441x; 1.1441x over previous
//
#include <hip/hip_runtime.h>

#define NT 256

// LDS layout: XOR swizzle, exact 32 KB (4096 float2) -> 5 blocks/CU by LDS.
// phys(l) = l ^ (((l>>4)&7)<<1): XORs the Q-digit (bits 4..6) into M-digit bits 1..3.
// Bijective. Conflict-free for every exchange pattern (bank-pair = phys mod 16):
//   ex1 w/r  l=256a+t:        bank4 = (t&15)^(((t>>4)&7)<<1)  bijection per 16-lane group
//   ex1r/ex2 l=256ax+16q+m2:  bank4 = m2^((q&7)<<1)           bijection in m2
//   ex2 b128 l=256ax+16m2+m:  bank4 = m^((m2&7)<<1)           uniform over even slots
// XOR leaves bit0 alone -> (2k,2k+1) pairs stay adjacent+ordered+16B-aligned for b128.
//
// NOTE launch_bounds is (NT,4), NOT (NT,5): 5 waves/EU capped the allocator at
// ~102 VGPRs and the compiler cut to 48 < natural 60 -> scratch spills
// (+75% FETCH, +79% WRITE, dur 88->122us). With (NT,4) the compiler allocates
// its natural ~60 VGPRs (<=64 -> no VGPR occupancy limit) and the HW still
// schedules 5 blocks/CU because LDS (32KB) is the binding resource.

// 16-point DFT in registers: v[k] = sum_j v[j] * w16^{jk}, w16 = e^{-2pi i/16}
// (INV=true: conjugated; unnormalized). Natural order in/out.
template<bool INV>
__device__ __forceinline__ void dft16(float* vr, float* vi) {
    constexpr float C1 = 0.9238795325112867f;   // cos(pi/8)
    constexpr float S1 = 0.3826834323650898f;   // sin(pi/8)
    constexpr float HF = 0.7071067811865476f;
    const float WR[10] = {1.f,  C1,  HF,  S1, 0.f, 0.f, -HF, 0.f, 0.f, -C1};
    const float WI[10] = {0.f, -S1, -HF, -C1, -1.f, 0.f, -HF, 0.f, 0.f,  S1};

    float ar[16], ai[16];
    #pragma unroll
    for (int jl = 0; jl < 4; ++jl) {
        float x0r = vr[jl],      x0i = vi[jl];
        float x1r = vr[jl + 4],  x1i = vi[jl + 4];
        float x2r = vr[jl + 8],  x2i = vi[jl + 8];
        float x3r = vr[jl + 12], x3i = vi[jl + 12];
        float t0r = x0r + x2r, t0i = x0i + x2i;
        float t1r = x0r - x2r, t1i = x0i - x2i;
        float t2r = x1r + x3r, t2i = x1i + x3i;
        float t3r = x1r - x3r, t3i = x1i - x3i;
        ar[jl]     = t0r + t2r;  ai[jl]     = t0i + t2i;
        ar[jl + 8] = t0r - t2r;  ai[jl + 8] = t0i - t2i;
        if (!INV) {
            ar[jl + 4]  = t1r + t3i;  ai[jl + 4]  = t1i - t3r;  // t1 - i*t3
            ar[jl + 12] = t1r - t3i;  ai[jl + 12] = t1i + t3r;  // t1 + i*t3
        } else {
            ar[jl + 4]  = t1r - t3i;  ai[jl + 4]  = t1i + t3r;
            ar[jl + 12] = t1r + t3i;  ai[jl + 12] = t1i - t3r;
        }
    }
    #pragma unroll
    for (int k4 = 1; k4 < 4; ++k4) {
        #pragma unroll
        for (int jl = 1; jl < 4; ++jl) {
            const int e = jl * k4;
            float wr = WR[e];
            float wi = INV ? -WI[e] : WI[e];
            const int id = jl + 4 * k4;
            float xr = ar[id], xi = ai[id];
            ar[id] = xr * wr - xi * wi;
            ai[id] = xr * wi + xi * wr;
        }
    }
    #pragma unroll
    for (int k4 = 0; k4 < 4; ++k4) {
        float x0r = ar[4*k4 + 0], x0i = ai[4*k4 + 0];
        float x1r = ar[4*k4 + 1], x1i = ai[4*k4 + 1];
        float x2r = ar[4*k4 + 2], x2i = ai[4*k4 + 2];
        float x3r = ar[4*k4 + 3], x3i = ai[4*k4 + 3];
        float t0r = x0r + x2r, t0i = x0i + x2i;
        float t1r = x0r - x2r, t1i = x0i - x2i;
        float t2r = x1r + x3r, t2i = x1i + x3i;
        float t3r = x1r - x3r, t3i = x1i - x3i;
        vr[k4]     = t0r + t2r;  vi[k4]     = t0i + t2i;
        vr[k4 + 8] = t0r - t2r;  vi[k4 + 8] = t0i - t2i;
        if (!INV) {
            vr[k4 + 4]  = t1r + t3i;  vi[k4 + 4]  = t1i - t3r;
            vr[k4 + 12] = t1r - t3i;  vi[k4 + 12] = t1i + t3r;
        } else {
            vr[k4 + 4]  = t1r - t3i;  vi[k4 + 4]  = t1i + t3r;
            vr[k4 + 12] = t1r + t3i;  vi[k4 + 12] = t1i - t3r;
        }
    }
}

// v[e] *= (wr,wi)^e for e=1..15; two independent chains stepping by w^2
// (halves the serial complex-mul chain latency vs a single chain).
__device__ __forceinline__ void apply_tw_powers(float* vr, float* vi, float wr, float wi) {
    const float w2r = wr * wr - wi * wi;
    const float w2i = 2.0f * wr * wi;
    float aor = wr,  aoi = wi;    // odd powers: w^1, w^3, ...
    float aer = w2r, aei = w2i;   // even powers: w^2, w^4, ...
    #pragma unroll
    for (int e = 1; e < 16; e += 2) {
        { float xr = vr[e], xi = vi[e];
          vr[e] = xr * aor - xi * aoi;
          vi[e] = xr * aoi + xi * aor; }
        if (e + 1 < 16) {
            float xr = vr[e + 1], xi = vi[e + 1];
            vr[e + 1] = xr * aer - xi * aei;
            vi[e + 1] = xr * aei + xi * aer;
        }
        if (e + 2 < 16) {
            float nr = aor * w2r - aoi * w2i, ni = aor * w2i + aoi * w2r;
            aor = nr; aoi = ni;
            nr = aer * w2r - aei * w2i; ni = aer * w2i + aei * w2r;
            aer = nr; aei = ni;
        }
    }
}

__global__ __launch_bounds__(NT, 4) void spectral_circulant_r16v5(
    const float* __restrict__ x,
    const float* __restrict__ w_real,
    const float* __restrict__ w_imag,
    const float* __restrict__ bias_p,
    float* __restrict__ out)
{
    __shared__ __align__(16) float2 lds[4096];   // exactly 32 KB -> 5 blocks/CU (HW, via LDS)

    const int t   = threadIdx.x;
    const int blk = blockIdx.x;

    float vr[16], vi[16];

    // ---- load two rows: z = rowA + i*rowB; reg j holds x[256j + t] ----
    const float* __restrict__ xa = x + (size_t)(2 * blk) * 4096;
    const float* __restrict__ xb = xa + 4096;
    #pragma unroll
    for (int j = 0; j < 16; ++j) {
        vr[j] = xa[(j << 8) + t];
        vi[j] = xb[(j << 8) + t];
    }

    // ---- stage A: DFT16 over j -> digit a; twiddle W4096^{t*a} ----
    dft16<false>(vr, vi);
    float sA, cA;
    __sincosf((float)t * -1.5339807878856412e-3f, &sA, &cA);  // -2pi/4096
    apply_tw_powers(vr, vi, cA, sA);

    // ---- exchange 1 write: l = 256a + t (b64); phys = 256a + tswz ----
    {
        const int tswz = t ^ ((t >> 3) & 0xE);   // t ^ (((t>>4)&7)<<1)
        #pragma unroll
        for (int a = 0; a < 16; ++a)
            lds[(a << 8) + tswz] = make_float2(vr[a], vi[a]);
    }
    __syncthreads();

    const int ax = t >> 4;               // upper digit this thread owns from here on
    const int m2 = t & 15;               // lower digit

    // 8 swizzled column bases: phys(256ax + 16q + m2) = swzbase[q&7] + 16q.
    // Shared by ex1-read, ex2-write, ex2-rev-read, ex1-rev-write (same l-set).
    int swzbase[8];
    #pragma unroll
    for (int c = 0; c < 8; ++c)
        swzbase[c] = (ax << 8) + (m2 ^ (c << 1));

    // ---- exchange 1 read: l = 256ax + 16q + m2 (b64) ----
    #pragma unroll
    for (int q = 0; q < 16; ++q) {
        float2 v = lds[swzbase[q & 7] + (q << 4)];
        vr[q] = v.x; vi[q] = v.y;
    }

    // ---- stage B: DFT16 over q -> digit b; twiddle W256^{m2*b} ----
    dft16<false>(vr, vi);
    float sB, cB;
    __sincosf((float)m2 * -2.454369260617026e-2f, &sB, &cB);  // -2pi/256
    apply_tw_powers(vr, vi, cB, sB);

    // ---- exchange 2 write: l = 256ax + 16b + m2 (b64) — same set this thread
    // read. Moves data only within 16 consecutive threads (same wave): per-wave
    // in-order DS pipe + compiler scheduling barrier suffice, no block barrier.
    #pragma unroll
    for (int b = 0; b < 16; ++b)
        lds[swzbase[b & 7] + (b << 4)] = make_float2(vr[b], vi[b]);
    __builtin_amdgcn_wave_barrier();

    // ---- exchange 2 read: 16 contiguous at l0 = 256ax + 16*m2;
    // phys = l0 + (m ^ c2), c2 even -> pairs stay aligned+ordered (b128) ----
    const int c2 = (m2 & 7) << 1;
    const float2* __restrict__ pbase = &lds[(ax << 8) + (m2 << 4)];
    #pragma unroll
    for (int m = 0; m < 16; m += 2) {
        float4 v = *(const float4*)&pbase[m ^ c2];
        vr[m] = v.x;     vi[m] = v.y;
        vr[m + 1] = v.z; vi[m + 1] = v.w;
    }

    // ---- stage C: DFT16 over m -> digit r3; freq k = 256*r3 + 16*m2 + ax ----
    dft16<false>(vr, vi);

    // ---- pointwise H[k]/N ----
    {
        const int c = (m2 << 4) | ax;            // 16*b + a  in [0,255]
        const float sc = 1.0f / 4096.0f;
        #pragma unroll
        for (int r3 = 0; r3 < 4; ++r3) {         // k < 1024: active
            const int k = (r3 << 8) + c;
            float hr = w_real[k] * sc;
            float hi = w_imag[k] * sc;
            float xr = vr[r3], xi = vi[r3];
            vr[r3] = xr * hr - xi * hi;
            vi[r3] = xr * hi + xi * hr;
        }
        #pragma unroll
        for (int r3 = 4; r3 < 12; ++r3) {        // k in [1024,3071]: truncated
            vr[r3] = 0.0f; vi[r3] = 0.0f;
        }
        {                                        // r3=12: k=3072+c, active iff c>0
            const int idx = 1024 - c;
            const float m = (c > 0) ? sc : 0.0f;
            float hr = w_real[idx] * m;
            float hi = -w_imag[idx] * m;
            float xr = vr[12], xi = vi[12];
            vr[12] = xr * hr - xi * hi;
            vi[12] = xr * hi + xi * hr;
        }
        #pragma unroll
        for (int r3 = 13; r3 < 16; ++r3) {       // k > 3072: conj mirror
            const int idx = ((16 - r3) << 8) - c;
            float hr = w_real[idx] * sc;
            float hi = -w_imag[idx] * sc;
            float xr = vr[r3], xi = vi[r3];
            vr[r3] = xr * hr - xi * hi;
            vi[r3] = xr * hi + xi * hr;
        }
    }

    // ================= inverse: exact adjoint, reverse order =================

    // ---- C^H: conj DFT16 over r3 -> m ----
    dft16<true>(vr, vi);

    // ---- exchange 2 reverse write: same contiguous-set addresses (b128) ----
    {
        float2* __restrict__ pw = &lds[(ax << 8) + (m2 << 4)];
        #pragma unroll
        for (int m = 0; m < 16; m += 2)
            *(float4*)&pw[m ^ c2] = make_float4(vr[m], vi[m], vr[m + 1], vi[m + 1]);
    }
    __builtin_amdgcn_wave_barrier();

    // ---- exchange 2 reverse read: l = 256ax + 16b + m2 over b (b64) ----
    #pragma unroll
    for (int b = 0; b < 16; ++b) {
        float2 v = lds[swzbase[b & 7] + (b << 4)];
        vr[b] = v.x; vi[b] = v.y;
    }

    // ---- B^H: conj twiddle, conj DFT16 over b -> q ----
    apply_tw_powers(vr, vi, cB, -sB);
    dft16<true>(vr, vi);

    // ---- exchange 1 reverse write: l = 256ax + 16q + m2 (same set, b64) ----
    #pragma unroll
    for (int q = 0; q < 16; ++q)
        lds[swzbase[q & 7] + (q << 4)] = make_float2(vr[q], vi[q]);
    __syncthreads();

    // ---- exchange 1 reverse read: l = 256a + t (b64) ----
    {
        const int tswz = t ^ ((t >> 3) & 0xE);
        #pragma unroll
        for (int a = 0; a < 16; ++a) {
            float2 v = lds[(a << 8) + tswz];
            vr[a] = v.x; vi[a] = v.y;
        }
    }

    // ---- A^H: conj twiddle, conj DFT16 over a -> j ----
    apply_tw_powers(vr, vi, cA, -sA);
    dft16<true>(vr, vi);

    // ---- store (nontemporal: streamed output) ----
    const float bv = bias_p[0];
    float* __restrict__ oa = out + (size_t)(2 * blk) * 4096;
    float* __restrict__ ob = oa + 4096;
    #pragma unroll
    for (int j = 0; j < 16; ++j) {
        __builtin_nontemporal_store(vr[j] + bv, &oa[(j << 8) + t]);
        __builtin_nontemporal_store(vi[j] + bv, &ob[(j << 8) + t]);
    }
}

extern "C" void kernel_launch(void* const* d_in, const int* in_sizes, int n_in,
                              void* d_out, int out_size, void* d_ws, size_t ws_size,
                              hipStream_t stream) {
    (void)in_sizes; (void)n_in; (void)d_ws; (void)ws_size; (void)out_size;
    const float* x      = (const float*)d_in[0];   // (8192, 4096) f32
    const float* w_real = (const float*)d_in[1];   // (2049,) f32
    const float* w_imag = (const float*)d_in[2];   // (2049,) f32
    const float* bias   = (const float*)d_in[3];   // scalar f32
    float* out = (float*)d_out;                    // (8192, 4096) f32

    spectral_circulant_r16v5<<<8192 / 2, NT, 0, stream>>>(x, w_real, w_imag, bias, out);
}